// Round 1
// baseline (2560.926 us; speedup 1.0000x reference)
//
#include <hip/hip_runtime.h>
#include <math.h>

// ---------------- utility ----------------
__device__ __forceinline__ float lrelu02(float v){ return v > 0.f ? v : 0.2f*v; }

__global__ void fill_int_k(int* p, int v, int n){
  int i = blockIdx.x*blockDim.x + threadIdx.x;
  if (i < n) p[i] = v;
}

__global__ void copy_int_k(int* dst, const int* src, int n){
  int i = blockIdx.x*blockDim.x + threadIdx.x;
  if (i < n) dst[i] = src[i];
}

// ---------------- CSR build (segment-by-dst) ----------------
__global__ void hist_dst_k(const int* __restrict__ ei, int E, int* deg){
  int e = blockIdx.x*blockDim.x + threadIdx.x;
  if (e < E) atomicAdd(&deg[ei[E + e]], 1);
}

__global__ void scan_k(const int* __restrict__ deg, int* rowptr, int n){
  __shared__ int s[1024];
  __shared__ int runS;
  int t = threadIdx.x;
  if (t == 0) runS = 0;
  __syncthreads();
  for (int base = 0; base < n; base += 1024){
    int v = (base + t < n) ? deg[base + t] : 0;
    s[t] = v; __syncthreads();
    for (int off = 1; off < 1024; off <<= 1){
      int x = (t >= off) ? s[t - off] : 0;
      __syncthreads();
      s[t] += x;
      __syncthreads();
    }
    int incl = s[t];
    int run = runS;
    if (base + t < n) rowptr[base + t] = run + incl - v;
    __syncthreads();
    if (t == 1023) runS = run + incl;
    __syncthreads();
  }
  if (t == 0) rowptr[n] = runS;
}

__global__ void fill_csr_k(const int* __restrict__ ei, int E, int* cursor, int* csr){
  int e = blockIdx.x*blockDim.x + threadIdx.x;
  if (e < E){
    int dst = ei[E + e];
    int pos = atomicAdd(&cursor[dst], 1);
    csr[pos] = ei[e];
  }
}

__global__ void self_loop_k(int* cursor, int* csr, int n){
  int i = blockIdx.x*blockDim.x + threadIdx.x;
  if (i < n){ int pos = atomicAdd(&cursor[i], 1); csr[pos] = i; }
}

// ---------------- attention score precompute ----------------
// As[f,h] = sum_c W1[f, h*128+c] * a_src[h,c]  (and same for Ad)
__global__ void make_as1_k(const float* __restrict__ W1, const float* __restrict__ a_src,
                           const float* __restrict__ a_dst, float* As, float* Ad){
  int idx = blockIdx.x*blockDim.x + threadIdx.x;
  if (idx < 78*10){
    int f = idx / 10, h = idx % 10;
    float ss = 0.f, sd = 0.f;
    for (int c = 0; c < 128; ++c){
      float w = W1[f*1280 + h*128 + c];
      ss += w * a_src[h*128 + c];
      sd += w * a_dst[h*128 + c];
    }
    As[idx] = ss; Ad[idx] = sd;
  }
}

// alpha_s[i,h] = x[i,:] . As[:,h]
__global__ void alpha1_k(const float* __restrict__ x, const float* __restrict__ As,
                         const float* __restrict__ Ad, float* as1, float* ad1, int n){
  int idx = blockIdx.x*blockDim.x + threadIdx.x;
  if (idx < n*10){
    int i = idx / 10, h = idx % 10;
    const float* xr = x + (long long)i*78;
    float ss = 0.f, sd = 0.f;
    for (int f = 0; f < 78; ++f){
      float xv = xr[f];
      ss += xv * As[f*10 + h];
      sd += xv * Ad[f*10 + h];
    }
    as1[idx] = ss; ad1[idx] = sd;
  }
}

// vs[k] = sum_c W2[k,c]*a_src2[c]
__global__ void make_vs2_k(const float* __restrict__ W2, const float* __restrict__ a_src,
                           const float* __restrict__ a_dst, float* vs, float* vd){
  int k = blockIdx.x*blockDim.x + threadIdx.x;
  if (k < 1280){
    float ss = 0.f, sd = 0.f;
    for (int c = 0; c < 128; ++c){
      float w = W2[k*128 + c];
      ss += w * a_src[c]; sd += w * a_dst[c];
    }
    vs[k] = ss; vd[k] = sd;
  }
}

__global__ __launch_bounds__(256)
void alpha2_k(const float* __restrict__ h1e, const float* __restrict__ vs,
              const float* __restrict__ vd, float* as2, float* ad2, int n){
  int i = blockIdx.x, t = threadIdx.x;
  __shared__ float ss[256], sd[256];
  const float* r = h1e + (long long)i*1280;
  float ps = 0.f, pd = 0.f;
  for (int k = t; k < 1280; k += 256){ float v = r[k]; ps += v*vs[k]; pd += v*vd[k]; }
  ss[t] = ps; sd[t] = pd; __syncthreads();
  for (int o = 128; o > 0; o >>= 1){
    if (t < o){ ss[t] += ss[t+o]; sd[t] += sd[t+o]; }
    __syncthreads();
  }
  if (t == 0){ as2[i] = ss[0]; ad2[i] = sd[0]; }
}

// ---------------- GATConv1 softmax + aggregate in input space ----------------
// y[i, h*78+f] = sum_{e: dst=i} alpha[e,h] * x[src_e, f]
__global__ __launch_bounds__(64)
void gat1_agg_k(const int* __restrict__ rowptr, const int* __restrict__ csr,
                const float* __restrict__ x, const float* __restrict__ as1,
                const float* __restrict__ ad1, float* __restrict__ y, int n){
  int i = blockIdx.x;
  int t = threadIdx.x;
  __shared__ float adi[10], mh[10], rden[10], wE[10], xs[78];
  int beg = rowptr[i], end = rowptr[i+1];
  if (t < 10){
    float a = ad1[i*10 + t];
    adi[t] = a;
    float m = -1e30f;
    for (int e = beg; e < end; ++e){
      int s = csr[e];
      m = fmaxf(m, lrelu02(as1[s*10 + t] + a));
    }
    float den = 0.f;
    for (int e = beg; e < end; ++e){
      int s = csr[e];
      den += expf(lrelu02(as1[s*10 + t] + a) - m);
    }
    mh[t] = m; rden[t] = 1.f/(den + 1e-16f);
  }
  __syncthreads();
  float acc[13];
  int hh[13], cc[13];
  #pragma unroll
  for (int k = 0; k < 13; ++k){
    acc[k] = 0.f;
    int j = t + 64*k;
    hh[k] = (j < 780) ? (j/78) : 0;
    cc[k] = (j < 780) ? (j%78) : 0;
  }
  for (int e = beg; e < end; ++e){
    int s = csr[e];
    if (t < 10) wE[t] = expf(lrelu02(as1[s*10 + t] + adi[t]) - mh[t]) * rden[t];
    for (int c = t; c < 78; c += 64) xs[c] = x[(long long)s*78 + c];
    __syncthreads();
    #pragma unroll
    for (int k = 0; k < 13; ++k){
      int j = t + 64*k;
      if (j < 780) acc[k] += wE[hh[k]] * xs[cc[k]];
    }
    __syncthreads();
  }
  #pragma unroll
  for (int k = 0; k < 13; ++k){
    int j = t + 64*k;
    if (j < 780) y[(long long)i*780 + j] = acc[k];
  }
}

// ---------------- GATConv2 softmax + aggregate (128-wide) ----------------
__global__ __launch_bounds__(64)
void gat2_agg_k(const int* __restrict__ rowptr, const int* __restrict__ csr,
                const float* __restrict__ h2, const float* __restrict__ as2,
                const float* __restrict__ ad2, const float* __restrict__ b2,
                float* __restrict__ h2e, int n){
  int i = blockIdx.x, t = threadIdx.x;
  int beg = rowptr[i], end = rowptr[i+1];
  float adi = ad2[i];
  float m = -1e30f;
  for (int e = beg; e < end; ++e) m = fmaxf(m, lrelu02(as2[csr[e]] + adi));
  float den = 0.f;
  for (int e = beg; e < end; ++e) den += expf(lrelu02(as2[csr[e]] + adi) - m);
  float rden = 1.f/(den + 1e-16f);
  float a0 = 0.f, a1 = 0.f;
  for (int e = beg; e < end; ++e){
    int s = csr[e];
    float w = expf(lrelu02(as2[s] + adi) - m) * rden;
    a0 += w * h2[(long long)s*128 + t];
    a1 += w * h2[(long long)s*128 + 64 + t];
  }
  float o0 = a0 + b2[t];      o0 = o0 > 0.f ? o0 : expm1f(o0);
  float o1 = a1 + b2[64 + t]; o1 = o1 > 0.f ? o1 : expm1f(o1);
  h2e[(long long)i*128 + t]      = o0;
  h2e[(long long)i*128 + 64 + t] = o1;
}

// ---------------- global max pool (batch is sorted) ----------------
__global__ __launch_bounds__(128)
void pool_k(const float* __restrict__ h2e, const int* __restrict__ batch, int n,
            float* __restrict__ pooled){
  int g = blockIdx.x, t = threadIdx.x;
  int lo = 0, hi = n;
  while (lo < hi){ int mid = (lo + hi) >> 1; if (batch[mid] < g) lo = mid + 1; else hi = mid; }
  int a = lo, b = n;
  while (a < b){ int mid = (a + b) >> 1; if (batch[mid] < g + 1) a = mid + 1; else b = mid; }
  float m = -1e30f;
  for (int i = lo; i < a; ++i) m = fmaxf(m, h2e[(long long)i*128 + t]);
  pooled[g*128 + t] = m;
}

// ---------------- row-wise L2 normalize ----------------
__global__ __launch_bounds__(256)
void l2norm_k(const float* __restrict__ in, float* __restrict__ out, int cols){
  int r = blockIdx.x, t = threadIdx.x;
  __shared__ float s[256];
  __shared__ float scaleS;
  const float* rp = in + (long long)r*cols;
  float p = 0.f;
  for (int k = t; k < cols; k += 256){ float v = rp[k]; p += v*v; }
  s[t] = p; __syncthreads();
  for (int o = 128; o > 0; o >>= 1){
    if (t < o) s[t] += s[t+o];
    __syncthreads();
  }
  if (t == 0) scaleS = 1.f / fmaxf(sqrtf(s[0]), 1e-12f);
  __syncthreads();
  float sc = scaleS;
  for (int k = t; k < cols; k += 256) out[(long long)r*cols + k] = rp[k]*sc;
}

__global__ void concat_k(const float* __restrict__ v1, const float* __restrict__ v2,
                         const float* __restrict__ c3, float* __restrict__ xcat, int B){
  int idx = blockIdx.x*blockDim.x + threadIdx.x;
  if (idx < B*512){
    int r = idx >> 9, c = idx & 511;
    float v;
    if (c < 128) v = v1[r*128 + c];
    else if (c < 256) v = v2[r*128 + (c - 128)];
    else v = c3[r*256 + (c - 256)];
    xcat[idx] = v;
  }
}

// ---------------- generic fp32 tiled GEMM: C = act(A@W + bias) ----------------
// A: [M,K] lda, W: [K,N] ldw, C: [M,N] ldc. batched via blockIdx.z with flat strides.
// act: 0=none 1=relu 2=elu
#define BM 64
#define BN 64
#define BK 16
__global__ __launch_bounds__(256)
void gemm_bias_act(const float* __restrict__ A, int lda, long long sA,
                   const float* __restrict__ W, int ldw, long long sW,
                   float* __restrict__ C, int ldc, long long sC,
                   const float* __restrict__ bias, int sBias, int hasBias,
                   int M, int Nc, int K, int act){
  int b = blockIdx.z;
  A += (long long)b * sA; W += (long long)b * sW; C += (long long)b * sC;
  if (hasBias) bias += (long long)b * sBias;
  __shared__ float As[BK][BM + 4];
  __shared__ float Ws[BK][BN + 4];
  int tid = threadIdx.x;
  int tx = tid & 15, ty = tid >> 4;
  int row0 = blockIdx.y * BM, col0 = blockIdx.x * BN;
  float acc[4][4] = {};
  for (int kt = 0; kt < K; kt += BK){
    for (int idx = tid; idx < BM*BK; idx += 256){
      int r = idx >> 4, kk = idx & 15;
      int gr = row0 + r, gk = kt + kk;
      As[kk][r] = (gr < M && gk < K) ? A[(long long)gr*lda + gk] : 0.f;
    }
    for (int idx = tid; idx < BK*BN; idx += 256){
      int kk = idx >> 6, n = idx & 63;
      int gk = kt + kk, gn = col0 + n;
      Ws[kk][n] = (gk < K && gn < Nc) ? W[(long long)gk*ldw + gn] : 0.f;
    }
    __syncthreads();
    #pragma unroll
    for (int kk = 0; kk < BK; ++kk){
      float a[4], w[4];
      #pragma unroll
      for (int i = 0; i < 4; ++i) a[i] = As[kk][ty*4 + i];
      #pragma unroll
      for (int j = 0; j < 4; ++j) w[j] = Ws[kk][tx*4 + j];
      #pragma unroll
      for (int i = 0; i < 4; ++i)
        #pragma unroll
        for (int j = 0; j < 4; ++j)
          acc[i][j] += a[i]*w[j];
    }
    __syncthreads();
  }
  #pragma unroll
  for (int i = 0; i < 4; ++i){
    int gr = row0 + ty*4 + i;
    if (gr >= M) continue;
    #pragma unroll
    for (int j = 0; j < 4; ++j){
      int gn = col0 + tx*4 + j;
      if (gn >= Nc) continue;
      float v = acc[i][j];
      if (hasBias) v += bias[gn];
      if (act == 1) v = fmaxf(v, 0.f);
      else if (act == 2) v = v > 0.f ? v : expm1f(v);
      C[(long long)gr*ldc + gn] = v;
    }
  }
}

// ---------------- host launch ----------------
extern "C" void kernel_launch(void* const* d_in, const int* in_sizes, int n_in,
                              void* d_out, int out_size, void* d_ws, size_t ws_size,
                              hipStream_t stream){
  const float* x1     = (const float*)d_in[0];
  const int*   ei1    = (const int*)  d_in[1];
  const int*   batch1 = (const int*)  d_in[2];
  const float* x2     = (const float*)d_in[3];
  const int*   ei2    = (const int*)  d_in[4];
  const int*   batch2 = (const int*)  d_in[5];
  const float* cell   = (const float*)d_in[6];
  const float* W1     = (const float*)d_in[7];
  const float* a_src1 = (const float*)d_in[8];
  const float* a_dst1 = (const float*)d_in[9];
  const float* b1     = (const float*)d_in[10];
  const float* W2     = (const float*)d_in[11];
  const float* a_src2 = (const float*)d_in[12];
  const float* a_dst2 = (const float*)d_in[13];
  const float* b2     = (const float*)d_in[14];
  const float* Wg     = (const float*)d_in[15];
  const float* bg     = (const float*)d_in[16];
  const float* Wr1    = (const float*)d_in[17];
  const float* br1    = (const float*)d_in[18];
  const float* Wr2    = (const float*)d_in[19];
  const float* br2    = (const float*)d_in[20];
  const float* Wr3    = (const float*)d_in[21];
  const float* br3    = (const float*)d_in[22];
  const float* Wf1    = (const float*)d_in[23];
  const float* bf1    = (const float*)d_in[24];
  const float* Wf2    = (const float*)d_in[25];
  const float* bf2    = (const float*)d_in[26];
  const float* Wf3    = (const float*)d_in[27];
  const float* bf3    = (const float*)d_in[28];
  const float* Wo     = (const float*)d_in[29];
  const float* bo     = (const float*)d_in[30];
  float* out = (float*)d_out;
  (void)n_in; (void)out_size; (void)ws_size;

  const int N  = in_sizes[0] / 78;
  const int E  = in_sizes[1] / 2;
  const int Bg = in_sizes[6] / 954;

  char* wsb = (char*)d_ws;
  size_t off = 0;
  auto alloc = [&](size_t bytes)->void*{
    void* p = wsb + off; off += ((bytes + 255)/256)*256; return p;
  };
  float* y    = (float*)alloc((size_t)N*780*4);     // also hosts aliased buffers below
  float* h1e  = (float*)alloc((size_t)N*1280*4);
  float* as1  = (float*)alloc((size_t)N*10*4);
  float* ad1  = (float*)alloc((size_t)N*10*4);
  float* as2  = (float*)alloc((size_t)N*4);
  float* ad2  = (float*)alloc((size_t)N*4);
  float* AsB  = (float*)alloc(780*4);
  float* AdB  = (float*)alloc(780*4);
  float* vs   = (float*)alloc(1280*4);
  float* vd   = (float*)alloc(1280*4);
  int* deg    = (int*)alloc((size_t)N*4);
  int* rowptr = (int*)alloc((size_t)(N+1)*4);
  int* cursor = (int*)alloc((size_t)N*4);
  int* csr    = (int*)alloc((size_t)(E+N)*4);
  float* pooled = (float*)alloc((size_t)Bg*128*4);
  float* v1   = (float*)alloc((size_t)Bg*128*4);
  float* v2   = (float*)alloc((size_t)Bg*128*4);
  // aliases into y (lifetimes disjoint with y's use as conv1 aggregate):
  float* h2  = y;                       // N*128, written after y consumed by GEMM1
  float* h2e = y + 4*1024*1024;         // N*128
  float* cb  = y + 8*1024*1024;         // cell/final MLP buffers (after both branches)
  float* cn   = cb;
  float* c1   = cn  + (size_t)Bg*954;
  float* c2   = c1  + (size_t)Bg*2048;
  float* c3   = c2  + (size_t)Bg*512;
  float* xcat = c3  + (size_t)Bg*256;
  float* xcn  = xcat+ (size_t)Bg*512;
  float* t1   = xcn + (size_t)Bg*512;
  float* t2   = t1  + (size_t)Bg*1024;
  float* t3   = t2  + (size_t)Bg*512;

  auto gemm = [&](const float* A, int lda, long long sA_,
                  const float* Wm, int ldw, long long sW_,
                  float* C, int ldc, long long sC_,
                  const float* bias, int sBias,
                  int M, int Nc, int K, int batch, int act){
    dim3 grid((Nc + 63)/64, (M + 63)/64, batch);
    gemm_bias_act<<<grid, 256, 0, stream>>>(A, lda, sA_, Wm, ldw, sW_, C, ldc, sC_,
                                            bias, sBias, bias != nullptr ? 1 : 0,
                                            M, Nc, K, act);
  };

  make_as1_k<<<(780 + 255)/256, 256, 0, stream>>>(W1, a_src1, a_dst1, AsB, AdB);
  make_vs2_k<<<(1280 + 255)/256, 256, 0, stream>>>(W2, a_src2, a_dst2, vs, vd);

  for (int br = 0; br < 2; ++br){
    const float* x   = br ? x2 : x1;
    const int* ei    = br ? ei2 : ei1;
    const int* batch = br ? batch2 : batch1;
    float* vout      = br ? v2 : v1;

    // CSR by dst (self-loops included via deg init = 1)
    fill_int_k<<<(N + 255)/256, 256, 0, stream>>>(deg, 1, N);
    hist_dst_k<<<(E + 255)/256, 256, 0, stream>>>(ei, E, deg);
    scan_k<<<1, 1024, 0, stream>>>(deg, rowptr, N);
    copy_int_k<<<(N + 255)/256, 256, 0, stream>>>(cursor, rowptr, N);
    fill_csr_k<<<(E + 255)/256, 256, 0, stream>>>(ei, E, cursor, csr);
    self_loop_k<<<(N + 255)/256, 256, 0, stream>>>(cursor, csr, N);

    // conv1
    alpha1_k<<<((N*10) + 255)/256, 256, 0, stream>>>(x, AsB, AdB, as1, ad1, N);
    gat1_agg_k<<<N, 64, 0, stream>>>(rowptr, csr, x, as1, ad1, y, N);
    // batched per-head GEMM: h1e[:, h*128: ] = elu( y[:, h*78: ] @ W1[:, h*128: ] + b1 )
    gemm(y, 780, 78, W1, 1280, 128, h1e, 1280, 128, b1, 128, N, 128, 78, 10, 2);

    // conv2
    alpha2_k<<<N, 256, 0, stream>>>(h1e, vs, vd, as2, ad2, N);
    gemm(h1e, 1280, 0, W2, 128, 0, h2, 128, 0, nullptr, 0, N, 128, 1280, 1, 0);
    gat2_agg_k<<<N, 64, 0, stream>>>(rowptr, csr, h2, as2, ad2, b2, h2e, N);

    // pool + linear
    pool_k<<<Bg, 128, 0, stream>>>(h2e, batch, N, pooled);
    gemm(pooled, 128, 0, Wg, 128, 0, vout, 128, 0, bg, 0, Bg, 128, 128, 1, 1);
  }

  // cell MLP
  l2norm_k<<<Bg, 256, 0, stream>>>(cell, cn, 954);
  gemm(cn, 954, 0, Wr1, 2048, 0, c1, 2048, 0, br1, 0, Bg, 2048, 954, 1, 1);
  gemm(c1, 2048, 0, Wr2, 512, 0, c2, 512, 0, br2, 0, Bg, 512, 2048, 1, 1);
  gemm(c2, 512, 0, Wr3, 256, 0, c3, 256, 0, br3, 0, Bg, 256, 512, 1, 1);

  // final MLP
  concat_k<<<((Bg*512) + 255)/256, 256, 0, stream>>>(v1, v2, c3, xcat, Bg);
  l2norm_k<<<Bg, 256, 0, stream>>>(xcat, xcn, 512);
  gemm(xcn, 512, 0, Wf1, 1024, 0, t1, 1024, 0, bf1, 0, Bg, 1024, 512, 1, 1);
  gemm(t1, 1024, 0, Wf2, 512, 0, t2, 512, 0, bf2, 0, Bg, 512, 1024, 1, 1);
  gemm(t2, 512, 0, Wf3, 128, 0, t3, 128, 0, bf3, 0, Bg, 128, 512, 1, 1);
  gemm(t3, 128, 0, Wo, 2, 0, out, 2, 0, bo, 0, Bg, 2, 128, 1, 0);
}